// Round 7
// baseline (309.311 us; speedup 1.0000x reference)
//
#include <hip/hip_runtime.h>

// Problem: L=200 events in pairs -> S=100 scan steps over u[N,N,3], N=256.
// Each (n,m) cell is an independent 100-step chain.
//
// History: r1 monolith ring (scattered dword loads): scan-part ~80 us;
// r4 4-lane/chain scattered: ~88 us (occupancy refuted); r5 split+LDS-staged:
// f+scan ~100 us total. Model: scattered 12-B/lane dword loads touch 3x the
// cache lines they use -> ~75 us floor, occupancy-invariant. Staged dwordx4
// has no waste -> floor ~25 us for the a-stream. This round (resubmit of r5
// design after infra failure; audited: barriers uniform, vmcnt exact, ring
// hazard fenced, bounds OK): ONE merged kernel, stage-first overlap, DRING=8,
// vmcnt counts pinned exact with sched_barrier(0).
//
// Layout: event_list[201,256,256], a[200,256,256,3], w[200,256,1,256],
//         u_begin[256,256,3], liner_w[256,3], liner_b[256], out[100,256,256].

#define NN    256
#define TT    200
#define SS    100
#define DRING 8            // LDS ring depth in groups (4 slabs = 2 steps each)

__global__ __launch_bounds__(256) void fused_kernel(
    const float* __restrict__ timep,   // [2]
    const float* __restrict__ ev,      // [201,N,N]
    const float* __restrict__ ub,      // [N,N,3]
    const float* __restrict__ a,       // [T,N,N,3]
    const float* __restrict__ w,       // [T,N,1,N]
    const float* __restrict__ lw,      // [N,3]
    const float* __restrict__ lb,      // [N]
    float* __restrict__ out)           // [S,N,N]
{
    __shared__ float stg[DRING][4][768];   // 96 KB ring: [buf][slab][m*3+c]
    __shared__ float fsl[TT];

    const int n    = blockIdx.x;
    const int tid  = threadIdx.x;
    const int lane = tid & 63;
    const int wv   = tid >> 6;             // wave id 0..3

    // per-lane global src for staging: 16 B/lane, 64 lanes = 1 KB/instruction
    const float* abase = a + (size_t)n * (NN * 3) + (size_t)lane * 4;

    // wave wv stages slab t=4q+wv of group q into stg[bidx][wv] (3 KB = 3 ops)
#define STAGE(qq, bidx)                                                        \
    do {                                                                       \
        const float* gp_ = abase + (size_t)(4 * (qq) + wv) * ((size_t)NN * NN * 3); \
        float* lp_ = &stg[bidx][wv][0];                                        \
        __builtin_amdgcn_global_load_lds(                                      \
            (const __attribute__((address_space(1))) void*)gp_,                \
            (__attribute__((address_space(3))) void*)lp_, 16, 0, 0);           \
        __builtin_amdgcn_global_load_lds(                                      \
            (const __attribute__((address_space(1))) void*)(gp_ + 256),        \
            (__attribute__((address_space(3))) void*)(lp_ + 256), 16, 0, 0);   \
        __builtin_amdgcn_global_load_lds(                                      \
            (const __attribute__((address_space(1))) void*)(gp_ + 512),        \
            (__attribute__((address_space(3))) void*)(lp_ + 512), 16, 0, 0);   \
    } while (0)

    // ---- issue stages for groups 0..6 FIRST: their HBM latency hides under
    //      the f-prologue's loads+compute ----
    STAGE(0, 0); STAGE(1, 1); STAGE(2, 2); STAGE(3, 3);
    STAGE(4, 4); STAGE(5, 5); STAGE(6, 6);

    // ---- f-prologue: fsl[t] = exp(-dot(w[t,n,:],ev[t,n,:]) * time[t&1]) ----
    // wave wv owns t = wv (mod 4): parity = wv&1, 50 t's per wave, 5/iter.
    {
        const float t0 = timep[0];
        const float t1 = timep[1];
        const float tsel = (wv & 1) ? t1 : t0;
        const size_t rowoff = (size_t)n * NN;
        const float* wrow = w  + rowoff;
        const float* erow = ev + rowoff;
        for (int t = wv; t < TT; t += 20) {          // 10 iterations
            float d[5];
#pragma unroll
            for (int q = 0; q < 5; ++q) {
                const int tq = t + 4 * q;            // <= wv+196 <= 199
                float4 wvv = ((const float4*)(wrow + (size_t)tq * (NN * NN)))[lane];
                float4 evv = ((const float4*)(erow + (size_t)tq * (NN * NN)))[lane];
                float dq = wvv.x * evv.x;
                dq = fmaf(wvv.y, evv.y, dq);
                dq = fmaf(wvv.z, evv.z, dq);
                dq = fmaf(wvv.w, evv.w, dq);
                d[q] = dq;
            }
#pragma unroll
            for (int o = 1; o < 64; o <<= 1) {
#pragma unroll
                for (int q = 0; q < 5; ++q) d[q] += __shfl_xor(d[q], o, 64);
            }
            if (lane == 0) {
#pragma unroll
                for (int q = 0; q < 5; ++q)
                    fsl[t + 4 * q] = __expf(-d[q] * tsel);
            }
        }
    }

    // ---- chain state + per-node constants ----
    const size_t cb = (size_t)n * (NN * 3) + (size_t)tid * 3;
    float u0 = ub[cb + 0], u1 = ub[cb + 1], u2 = ub[cb + 2];
    const float w0 = lw[n * 3 + 0];
    const float w1 = lw[n * 3 + 1];
    const float w2 = lw[n * 3 + 2];
    const float bb = lb[n];
    const int m3 = tid * 3;
    float* op = out + (size_t)n * NN + tid;

    // drains vmcnt(0)+lgkmcnt(0): prologue loads, fsl writes AND the 21
    // prestaged loads all complete here -> vmcnt base is 0 for the phases.
    __syncthreads();

#define STEPX(BI, SA, SB, FA, FB, SOUT)                                        \
    do {                                                                       \
        float l0 = fmaf(stg[BI][SA][m3 + 0], FA, fmaf(stg[BI][SB][m3 + 0], FB, u0)); \
        float l1 = fmaf(stg[BI][SA][m3 + 1], FA, fmaf(stg[BI][SB][m3 + 1], FB, u1)); \
        float l2 = fmaf(stg[BI][SA][m3 + 2], FA, fmaf(stg[BI][SB][m3 + 2], FB, u2)); \
        float mx = fmaxf(l0, fmaxf(l1, l2));                                   \
        float e0 = __expf(l0 - mx), e1 = __expf(l1 - mx), e2 = __expf(l2 - mx);\
        float iv = __builtin_amdgcn_rcpf(e0 + e1 + e2);                        \
        u0 = e0 * iv; u1 = e1 * iv; u2 = e2 * iv;                              \
        __builtin_nontemporal_store(fmaf(u0, w0, fmaf(u1, w1, fmaf(u2, w2, bb))), \
                                    op + (size_t)(SOUT) * (NN * NN));          \
    } while (0)

    // Phase g: wait via exact counted vmcnt (order pinned by sched_barrier(0):
    // [stores | vmcnt | stage | steps+stores]), barrier, stage group g+7 into
    // buf (g-1)%8, consume group g (steps 2g, 2g+1).
#define PHASE(GG, VN, DOSTAGE, BI)                                             \
    do {                                                                       \
        asm volatile("s_waitcnt vmcnt(" #VN ")" ::: "memory");                 \
        __builtin_amdgcn_sched_barrier(0);                                     \
        __builtin_amdgcn_s_barrier();                                          \
        if (DOSTAGE) {                                                         \
            const int bs_ = (BI) ? (BI) - 1 : (DRING - 1);                     \
            STAGE((GG) + DRING - 1, bs_);                                      \
        }                                                                      \
        __builtin_amdgcn_sched_barrier(0);                                     \
        const float fa0 = fsl[4 * (GG) + 0], fb0 = fsl[4 * (GG) + 1];          \
        STEPX(BI, 0, 1, fa0, fb0, 2 * (GG));                                   \
        const float fa1 = fsl[4 * (GG) + 2], fb1 = fsl[4 * (GG) + 3];          \
        STEPX(BI, 2, 3, fa1, fb1, 2 * (GG) + 1);                               \
    } while (0)

    // vmcnt(N) = #vm-ops younger than group g's stage at this wait (exact for
    // g>=7; early phases' prestages were drained by the barrier -> no-ops):
    // steady g=7..43: 2 stores + 6 phases x 5 = 32; tail shrinks by 3/phase
    // while stores add 2 -> 29,26,23,20,17,14.
    PHASE(0, 18, 1, 0);
    PHASE(1, 20, 1, 1);
    PHASE(2, 22, 1, 2);
    PHASE(3, 24, 1, 3);
    PHASE(4, 26, 1, 4);
    PHASE(5, 28, 1, 5);
    PHASE(6, 30, 1, 6);
    {
        int b = 7;                        // b == g % 8, rolled manually
        for (int g = 7; g <= 42; ++g) {
            PHASE(g, 32, 1, b);
            b = (b + 1) & 7;
        }
    }
    PHASE(43, 32, 0, 3);
    PHASE(44, 29, 0, 4);
    PHASE(45, 26, 0, 5);
    PHASE(46, 23, 0, 6);
    PHASE(47, 20, 0, 7);
    PHASE(48, 17, 0, 0);
    PHASE(49, 14, 0, 1);

#undef PHASE
#undef STEPX
#undef STAGE
}

extern "C" void kernel_launch(void* const* d_in, const int* in_sizes, int n_in,
                              void* d_out, int out_size, void* d_ws, size_t ws_size,
                              hipStream_t stream) {
    const float* timep = (const float*)d_in[0];
    const float* ev    = (const float*)d_in[1];
    const float* ub    = (const float*)d_in[2];
    const float* a     = (const float*)d_in[3];
    const float* w     = (const float*)d_in[4];
    const float* lw    = (const float*)d_in[5];
    const float* lb    = (const float*)d_in[6];
    float* out = (float*)d_out;

    fused_kernel<<<NN, 256, 0, stream>>>(timep, ev, ub, a, w, lw, lb, out);
}